// Round 6
// baseline (228.879 us; speedup 1.0000x reference)
//
#include <hip/hip_runtime.h>

#define N_NODES 100000
#define N_EDGES 3200000
#define IN_DIM 128
#define HID_DIM 64
#define OUT_DIM 2
#define N_GRAPHS 512

#define BSHIFT 6
#define NBK 1563           // ceil(100000/64) buckets of 64 nodes
#define NBB 1024           // blocks in the binning pass (4/CU: 32 waves/CU, 1 round)
#define EPB2 3125          // edges per bin-block (1024*3125 = 3.2M exact)
#define CAPSHIFT 12        // 4096 slots per bucket in binned (mean ~2046, max ~2300)
#define LDS_E2 2816        // per-bucket LDS edge capacity (8-aligned lists incl. self)
#define ZERO_ROW N_NODES   // all-zero fp8 row used for alignment padding

__device__ inline unsigned short f2bf(float f) {
    union { float f; unsigned int i; } v; v.f = f;
    unsigned int r = v.i + 0x7fffu + ((v.i >> 16) & 1u);
    return (unsigned short)(r >> 16);
}

typedef __attribute__((ext_vector_type(8))) short bf16x8;
typedef __attribute__((ext_vector_type(4))) float f32x4;
typedef __attribute__((ext_vector_type(2))) float f32x2;

// ---- pass 0: zero cnt_g/gsum/gcnt + ZERO_ROW (replaces all memsets) -----
__global__ __launch_bounds__(1024) void k_init(float* __restrict__ gsum,
                                               int* __restrict__ cnt_g,
                                               float* __restrict__ gcnt,
                                               unsigned char* __restrict__ xws) {
    int b = blockIdx.x, t = threadIdx.x;
    if (b < 32) {
        gsum[b * 1024 + t] = 0.f;                     // 32768 floats
    } else if (b < 34) {
        int j = (b - 32) * 1024 + t;
        if (j < NBK) cnt_g[j] = 0;
    } else {
        if (t < N_GRAPHS) gcnt[t] = 0.f;
        if (t >= 1008)
            ((int*)(xws + (size_t)ZERO_ROW * HID_DIM))[t - 1008] = 0;
    }
}

// ---- pass 1: fused hist + dynamic-reservation scatter --------------------
// LATENCY-BOUND kernel -> maximize wave concurrency: no colbuf (col is
// re-read in pass B, L2/L3-warm), LDS = h+cur only (12.5 KB) so 4 blocks/CU
// (wave-capped) and grid NBB=1024 fills all CUs in ONE round (32 waves/CU;
// R4's 62.5KB colbuf variant ran 1 block/CU @ 19% occupancy -> 50+ us).
// Reservation: base = atomicAdd(&cnt_g[bk], h[bk]); fixed-stride bucket
// array binned[bk*4096 + base + rk]. Within-bucket order nondeterministic
// (always was, via atomic rk).
__global__ __launch_bounds__(512) void k_bin(const int* __restrict__ row,
                                             const int* __restrict__ col,
                                             int* __restrict__ cnt_g,
                                             int* __restrict__ binned) {
    __shared__ int h[NBK];
    __shared__ int cur[NBK];
    for (int i = threadIdx.x; i < NBK; i += 512) { h[i] = 0; cur[i] = 0; }
    __syncthreads();
    int s = blockIdx.x * EPB2, e = s + EPB2;
    for (int i = s + threadIdx.x; i < e; i += 512)
        atomicAdd(&h[col[i] >> BSHIFT], 1);
    __syncthreads();
    for (int i = threadIdx.x; i < NBK; i += 512) {
        int hv = h[i];
        if (hv) h[i] = (i << CAPSHIFT) + atomicAdd(&cnt_g[i], hv);
    }
    __syncthreads();
    for (int i = s + threadIdx.x; i < e; i += 512) {
        int c = col[i];                    // L2-warm re-read
        int r = row[i];
        int bk = c >> BSHIFT;
        int rk = atomicAdd(&cur[bk], 1);
        binned[h[bk] + rk] = ((c & 63) << 17) | r;   // pk: local nid | src row
    }
}

// ---- xws = (x @ W_gcn) * dinv via MFMA, output fp8 e4m3 ------------------
// Block == bucket: degree hist fused here (replaces k_deg). Hist's global
// loads + LDS atomics issue BEFORE the MFMA loop and complete under it;
// barrier only before the epilogue that needs cnt. cnt is also spilled to
// degs[] so k_aggrf needn't re-read binned for its own hist. Wave computes
// 16-node x 64-col tile with mfma_f32_16x16x32_bf16; C/D: col=lane&15,
// row=quad*4+reg.
__global__ __launch_bounds__(256) void k_gemm(const float* __restrict__ x,
                                              const float* __restrict__ Wg,
                                              const int* __restrict__ cnt_g,
                                              const int* __restrict__ binned,
                                              int* __restrict__ degs,
                                              unsigned char* __restrict__ xws) {
    __shared__ unsigned short wb[16][64][8];   // [ks*4+nt][lane][j]  16 KB
    __shared__ int cnt[64];

    if (threadIdx.x < 64) cnt[threadIdx.x] = 0;
    for (int idx = threadIdx.x; idx < 1024; idx += 256) {
        int f = idx >> 6, l = idx & 63;
        int ks = f >> 2, nt = f & 3;
        int n = (l & 15) + (nt << 4);
        int kbase = (ks << 5) + ((l >> 4) << 3);
        unsigned short tmp[8];
#pragma unroll
        for (int j = 0; j < 8; j++)
            tmp[j] = f2bf(Wg[(kbase + j) * HID_DIM + n]);
        *(bf16x8*)&wb[f][l][0] = *(const bf16x8*)tmp;
    }
    __syncthreads();

    int bkt = blockIdx.x;
    int m = cnt_g[bkt];
    for (int i = threadIdx.x; i < m; i += 256)          // deg hist (overlaps MFMA)
        atomicAdd(&cnt[binned[(bkt << CAPSHIFT) + i] >> 17], 1);

    int wave = threadIdx.x >> 6;
    int lane = threadIdx.x & 63;
    int q = lane >> 4, nn = lane & 15;

    bf16x8 bfrag[4][4];
#pragma unroll
    for (int ks = 0; ks < 4; ks++)
#pragma unroll
        for (int nt = 0; nt < 4; nt++)
            bfrag[ks][nt] = *(const bf16x8*)&wb[ks * 4 + nt][lane][0];

    int node0 = bkt * 64 + wave * 16;
    int arow = node0 + nn;
    if (arow > N_NODES - 1) arow = N_NODES - 1;   // clamp (stores predicated)
    const float* xrow = x + (size_t)arow * IN_DIM + (q << 3);

    f32x4 acc[4] = {{0.f,0.f,0.f,0.f},{0.f,0.f,0.f,0.f},
                    {0.f,0.f,0.f,0.f},{0.f,0.f,0.f,0.f}};
#pragma unroll
    for (int ks = 0; ks < 4; ks++) {
        float4 xa = *(const float4*)(xrow + ks * 32);
        float4 xb_ = *(const float4*)(xrow + ks * 32 + 4);
        bf16x8 af;
        af[0] = (short)f2bf(xa.x); af[1] = (short)f2bf(xa.y);
        af[2] = (short)f2bf(xa.z); af[3] = (short)f2bf(xa.w);
        af[4] = (short)f2bf(xb_.x); af[5] = (short)f2bf(xb_.y);
        af[6] = (short)f2bf(xb_.z); af[7] = (short)f2bf(xb_.w);
#pragma unroll
        for (int nt = 0; nt < 4; nt++)
            acc[nt] = __builtin_amdgcn_mfma_f32_16x16x32_bf16(af, bfrag[ks][nt], acc[nt], 0, 0, 0);
    }
    __syncthreads();                                    // cnt hist complete

    if (threadIdx.x < 64) degs[bkt * 64 + threadIdx.x] = cnt[threadIdx.x];

#pragma unroll
    for (int r = 0; r < 4; r++) {
        int lrow = wave * 16 + q * 4 + r;
        int mrow = bkt * 64 + lrow;
        if (mrow < N_NODES) {
            float dn = rsqrtf((float)cnt[lrow] + 1.0f);
            int p01 = __builtin_amdgcn_cvt_pk_fp8_f32(acc[0][r] * dn, acc[1][r] * dn, 0, false);
            int p23 = __builtin_amdgcn_cvt_pk_fp8_f32(acc[2][r] * dn, acc[3][r] * dn, 0, false);
            unsigned char* rp = xws + (size_t)mrow * HID_DIM + nn;
            rp[0]  = (unsigned char)(p01 & 0xff);
            rp[16] = (unsigned char)((p01 >> 8) & 0xff);
            rp[32] = (unsigned char)(p23 & 0xff);
            rp[48] = (unsigned char)((p23 >> 8) & 0xff);
        }
    }
}

// ---- fused local-CSR build + gather-aggregate + ReLU + mean-pool ---------
// 512-thread block per 64-node bucket. Degrees come from degs[] (written
// by k_gemm) -> no binned re-read for hist. srt holds BYTE offsets
// (row<<6). Subset-per-node gather: each 16-lane subset owns ONE node
// end-to-end -> zero-shuffle epilogue. Lists 8-aligned with self-loop
// folded in; 8 slots/iter (2x ds_read_b128 + 8 row-loads in flight) with 4
// independent accumulator chains. Per-graph node counts (gcnt) accumulated
// here so k_mlp needs no binary search.
__global__ __launch_bounds__(512) void k_aggrf(const unsigned char* __restrict__ xws,
                                               const int* __restrict__ binned,
                                               const int* __restrict__ cnt_g,
                                               const int* __restrict__ degs,
                                               const int* __restrict__ batch,
                                               const float* __restrict__ bg,
                                               float* __restrict__ gsum,
                                               float* __restrict__ gcnt) {
    int bkt = blockIdx.x;
    int nbase = bkt << BSHIFT;
    int nnodes = N_NODES - nbase; if (nnodes > 64) nnodes = 64;
    int m = cnt_g[bkt];
    int base = bkt << CAPSHIFT;

    __shared__ int cnt[64];
    __shared__ int lptr[65];
    __shared__ int cur[64];
    __shared__ int sb[64];
    __shared__ float gcl[8];
    __shared__ alignas(16) int srt[LDS_E2];
    __shared__ float pool[8][4][64];   // [wave][graph-slot][col]

    if (threadIdx.x < 64) {
        int n = nbase + threadIdx.x;
        cnt[threadIdx.x] = (threadIdx.x < nnodes) ? degs[bkt * 64 + threadIdx.x] : 0;
        sb[threadIdx.x]  = (threadIdx.x < nnodes) ? batch[n] : 0;
        cur[threadIdx.x] = 0;
    }
    if (threadIdx.x < 8) gcl[threadIdx.x] = 0.f;
    for (int t = threadIdx.x; t < 8 * 4 * 64; t += 512)
        ((float*)pool)[t] = 0.f;
    __syncthreads();

    // wave-parallel 8-aligned inclusive scan (wave 0); +1 slot for self
    if (threadIdx.x < 64) {
        int v = (threadIdx.x < nnodes) ? ((cnt[threadIdx.x] + 8) & ~7) : 0;
        int run = v;
#pragma unroll
        for (int off = 1; off < 64; off <<= 1) {
            int t = __shfl_up(run, off);
            if (threadIdx.x >= off) run += t;
        }
        lptr[threadIdx.x + 1] = run;
        if (threadIdx.x == 0) lptr[0] = 0;
    }
    __syncthreads();
    int tot = lptr[64]; if (tot > LDS_E2) tot = LDS_E2;
    for (int i = threadIdx.x; i < tot; i += 512) srt[i] = ZERO_ROW << 6;
    __syncthreads();
    // self slot (right after the node's edges) + per-graph node counts
    if (threadIdx.x < nnodes) {
        int p = lptr[threadIdx.x] + cnt[threadIdx.x];
        if (p < LDS_E2) srt[p] = (nbase + threadIdx.x) << 6;
        int sl = sb[threadIdx.x] - sb[0];
        if (sl < 8) atomicAdd(&gcl[sl], 1.0f);
        else atomicAdd(&gcnt[sb[threadIdx.x]], 1.0f);
    }
    for (int i = threadIdx.x; i < m; i += 512) {        // CSR scatter
        int pk = binned[base + i];
        int nid = pk >> 17;
        int rk = atomicAdd(&cur[nid], 1);
        int pos = lptr[nid] + rk;
        if (pos < LDS_E2) srt[pos] = (pk & 0x1FFFF) << 6;   // byte offset
    }
    __syncthreads();

    int wave = threadIdx.x >> 6;
    int lane = threadIdx.x & 63;
    int sub = lane >> 4;                // subset: owns one node at a time
    int lc  = lane & 15;                // lane-in-subset: cols 4lc..4lc+3
    int l4  = lc << 2;                  // byte offset of that dword in a row
    const unsigned char* xbl = xws + l4;
    int g0 = sb[0];
    float4 bia = ((const float4*)bg)[lc];

#pragma unroll
    for (int r = 0; r < 2; r++) {
        int ln = wave * 8 + sub * 2 + r;          // 32 processors x 2 rounds
        int valid = (ln < nnodes);
        int s0 = valid ? lptr[ln] : 0;
        int e0 = valid ? lptr[ln + 1] : 0;
        if (s0 > LDS_E2) s0 = LDS_E2;
        if (e0 > LDS_E2) e0 = LDS_E2;             // both multiples of 8
        f32x2 al0 = {0.f,0.f}, ah0 = {0.f,0.f};   // 4 independent chains
        f32x2 al1 = {0.f,0.f}, ah1 = {0.f,0.f};
        for (int i = s0; i < e0; i += 8) {        // divergent across subsets
            int4 ra = *(const int4*)&srt[i];      // subset-uniform broadcast
            int4 rb = *(const int4*)&srt[i + 4];
            unsigned int d0 = *(const unsigned int*)(xbl + ra.x);
            unsigned int d1 = *(const unsigned int*)(xbl + ra.y);
            unsigned int d2 = *(const unsigned int*)(xbl + ra.z);
            unsigned int d3 = *(const unsigned int*)(xbl + ra.w);
            unsigned int d4 = *(const unsigned int*)(xbl + rb.x);
            unsigned int d5 = *(const unsigned int*)(xbl + rb.y);
            unsigned int d6 = *(const unsigned int*)(xbl + rb.z);
            unsigned int d7 = *(const unsigned int*)(xbl + rb.w);
            f32x2 p;
            p = __builtin_amdgcn_cvt_pk_f32_fp8(d0, false); al0 += p;
            p = __builtin_amdgcn_cvt_pk_f32_fp8(d0, true);  ah0 += p;
            p = __builtin_amdgcn_cvt_pk_f32_fp8(d1, false); al1 += p;
            p = __builtin_amdgcn_cvt_pk_f32_fp8(d1, true);  ah1 += p;
            p = __builtin_amdgcn_cvt_pk_f32_fp8(d2, false); al0 += p;
            p = __builtin_amdgcn_cvt_pk_f32_fp8(d2, true);  ah0 += p;
            p = __builtin_amdgcn_cvt_pk_f32_fp8(d3, false); al1 += p;
            p = __builtin_amdgcn_cvt_pk_f32_fp8(d3, true);  ah1 += p;
            p = __builtin_amdgcn_cvt_pk_f32_fp8(d4, false); al0 += p;
            p = __builtin_amdgcn_cvt_pk_f32_fp8(d4, true);  ah0 += p;
            p = __builtin_amdgcn_cvt_pk_f32_fp8(d5, false); al1 += p;
            p = __builtin_amdgcn_cvt_pk_f32_fp8(d5, true);  ah1 += p;
            p = __builtin_amdgcn_cvt_pk_f32_fp8(d6, false); al0 += p;
            p = __builtin_amdgcn_cvt_pk_f32_fp8(d6, true);  ah0 += p;
            p = __builtin_amdgcn_cvt_pk_f32_fp8(d7, false); al1 += p;
            p = __builtin_amdgcn_cvt_pk_f32_fp8(d7, true);  ah1 += p;
        }
        f32x2 alo = al0 + al1, ahi = ah0 + ah1;
        int slot = 99;
        float4 val;
        if (valid) {
            float dn = rsqrtf((float)cnt[ln] + 1.0f);
            val.x = fmaxf(alo[0] * dn + bia.x, 0.f);
            val.y = fmaxf(alo[1] * dn + bia.y, 0.f);
            val.z = fmaxf(ahi[0] * dn + bia.z, 0.f);
            val.w = fmaxf(ahi[1] * dn + bia.w, 0.f);
            slot = sb[ln] - g0;
        }
        // serialize the 4 subsets' pool RMW (same wave -> in-order LDS ops)
#pragma unroll
        for (int ss = 0; ss < 4; ss++) {
            if (sub == ss && slot < 4) {
                float4* pp = (float4*)&pool[wave][slot][l4];
                float4 pv = *pp;
                pv.x += val.x; pv.y += val.y; pv.z += val.z; pv.w += val.w;
                *pp = pv;
            }
        }
        if (slot >= 4 && slot < 99) {             // rare: >4 graphs in window
            float* gp = &gsum[sb[ln] * HID_DIM + l4];
            atomicAdd(gp + 0, val.x); atomicAdd(gp + 1, val.y);
            atomicAdd(gp + 2, val.z); atomicAdd(gp + 3, val.w);
        }
    }
    __syncthreads();

    if (threadIdx.x < 8) {
        float c = gcl[threadIdx.x];
        if (c != 0.f) atomicAdd(&gcnt[g0 + threadIdx.x], c);
    }
    for (int t = threadIdx.x; t < 4 * 64; t += 512) {
        int slot = t >> 6, j = t & 63;
        float v = 0.f;
#pragma unroll
        for (int w2 = 0; w2 < 8; w2++) v += pool[w2][slot][j];
        if (v != 0.f) atomicAdd(&gsum[(g0 + slot) * HID_DIM + j], v);
    }
}

// ---- divide by counts + MLP + sigmoid (one wave per graph) ---------------
__global__ __launch_bounds__(64) void k_mlp(const float* __restrict__ gsum,
                                            const float* __restrict__ gcnt,
                                            const float* __restrict__ W1,
                                            const float* __restrict__ b1,
                                            const float* __restrict__ W2,
                                            const float* __restrict__ b2,
                                            float* __restrict__ out) {
    int g = blockIdx.x;
    int j = threadIdx.x;
    float cnt = fmaxf(gcnt[g], 1.0f);

    __shared__ float gs[64];
    __shared__ float hs[64];
    gs[j] = gsum[g * 64 + j] / cnt;
    __syncthreads();

    float h = b1[j];
    for (int k = 0; k < 64; k++) h += gs[k] * W1[k * 64 + j];
    hs[j] = fmaxf(h, 0.f);
    __syncthreads();

    if (j < OUT_DIM) {
        float o = b2[j];
        for (int k = 0; k < 64; k++) o += hs[k] * W2[k * OUT_DIM + j];
        out[g * OUT_DIM + j] = 1.f / (1.f + expf(-o));
    }
}

extern "C" void kernel_launch(void* const* d_in, const int* in_sizes, int n_in,
                              void* d_out, int out_size, void* d_ws, size_t ws_size,
                              hipStream_t stream) {
    const float* x   = (const float*)d_in[0];
    const int* eidx  = (const int*)d_in[1];
    const int* batch = (const int*)d_in[2];
    const float* Wg  = (const float*)d_in[3];
    const float* bg  = (const float*)d_in[4];
    const float* W1  = (const float*)d_in[5];
    const float* b1  = (const float*)d_in[6];
    const float* W2  = (const float*)d_in[7];
    const float* b2  = (const float*)d_in[8];
    float* out = (float*)d_out;

    // workspace layout (~31.1 MiB)
    char* w = (char*)d_ws;
    unsigned char* xws = (unsigned char*)w;     w += (size_t)(N_NODES + 1) * HID_DIM;    // 6.4 MB (fp8)
    int*   binned  = (int*)w;                   w += ((size_t)NBK << CAPSHIFT) * 4;      // 25.6 MB fixed-stride
    int*   cnt_g   = (int*)w;                   w += NBK * 4;
    int*   degs    = (int*)w;                   w += (size_t)NBK * 64 * 4;               // 400 KB
    float* gsum    = (float*)w;                 w += N_GRAPHS * HID_DIM * 4;             // 131 KB
    float* gcnt    = (float*)w;                 w += N_GRAPHS * 4;                       // 2 KB

    const int* rowp = eidx;             // edge_index[0] (sources)
    const int* colp = eidx + N_EDGES;   // edge_index[1] (destinations)

    k_init<<<35, 1024, 0, stream>>>(gsum, cnt_g, gcnt, xws);
    k_bin<<<NBB, 512, 0, stream>>>(rowp, colp, cnt_g, binned);
    k_gemm<<<NBK, 256, 0, stream>>>(x, Wg, cnt_g, binned, degs, xws);
    k_aggrf<<<NBK, 512, 0, stream>>>(xws, binned, cnt_g, degs, batch, bg, gsum, gcnt);
    k_mlp<<<N_GRAPHS, 64, 0, stream>>>(gsum, gcnt, W1, b1, W2, b2, out);
}

// Round 7
// 198.747 us; speedup vs baseline: 1.1516x; 1.1516x over previous
//
#include <hip/hip_runtime.h>

#define N_NODES 100000
#define N_EDGES 3200000
#define IN_DIM 128
#define HID_DIM 64
#define OUT_DIM 2
#define N_GRAPHS 512

#define BSHIFT 6
#define NBUCK 1564         // ceil(100000/64)=1563, padded so NBUCK*NB3 % 1024 == 0
#define NB3 256            // blocks in hist/scatter passes
#define EPB 12500          // edges per block (256*12500 = 3.2M exact)
#define NSB 391            // scan blocks: 1564*256/1024
#define LDS_E2 2816        // per-bucket edge capacity (8-aligned lists: mean ~2336, ~10 sd slack)
#define ZERO_ROW N_NODES   // all-zero fp8 row used for alignment padding

// XCD-swizzled block column (NB3=256): blocks b, b+8, b+16.. (same XCD under
// %8 dispatch) get ADJACENT slots, so a 64B line is written by one XCD's L2.
// R6 lesson: scatter WRITE locality (32B runs, line sharing) beats occupancy
// — 1024-block dynamic reservation amplified HBM writes 7.7x and lost 27 us.
__device__ inline int xcol(int b) { return ((b & 7) << 5) | (b >> 3); }

__device__ inline unsigned short f2bf(float f) {
    union { float f; unsigned int i; } v; v.f = f;
    unsigned int r = v.i + 0x7fffu + ((v.i >> 16) & 1u);
    return (unsigned short)(r >> 16);
}

typedef __attribute__((ext_vector_type(8))) short bf16x8;
typedef __attribute__((ext_vector_type(4))) float f32x4;
typedef __attribute__((ext_vector_type(2))) float f32x2;

// ---- pass 1: per-block LDS histogram over 1564 coarse buckets ------------
__global__ __launch_bounds__(512) void k_hist(const int* __restrict__ col,
                                              int* __restrict__ H) {
    __shared__ int h[NBUCK];
    for (int i = threadIdx.x; i < NBUCK; i += 512) h[i] = 0;
    __syncthreads();
    int b = blockIdx.x;
    int bb = xcol(b);
    int s = b * EPB, e = s + EPB;
    for (int i = s + threadIdx.x; i < e; i += 512)
        atomicAdd(&h[col[i] >> BSHIFT], 1);
    __syncthreads();
    for (int i = threadIdx.x; i < NBUCK; i += 512)
        H[i * NB3 + bb] = h[i];                   // bucket-major, swizzled col
}

// ---- pass 2a: local exclusive scan of the 400384-entry matrix ------------
__global__ __launch_bounds__(1024) void k_scan_a(const int* __restrict__ H,
                                                 int* __restrict__ OFF,
                                                 int* __restrict__ bsum) {
    __shared__ int lds[1024];
    int i = blockIdx.x * 1024 + threadIdx.x;
    int v = H[i];
    lds[threadIdx.x] = v;
    __syncthreads();
    for (int off = 1; off < 1024; off <<= 1) {
        int t = (threadIdx.x >= off) ? lds[threadIdx.x - off] : 0;
        __syncthreads();
        lds[threadIdx.x] += t;
        __syncthreads();
    }
    OFF[i] = lds[threadIdx.x] - v;
    if (threadIdx.x == 1023) bsum[blockIdx.x] = lds[1023];
}

// ---- pass 2b: finalize with block-sum prefix; zero gsum/gcnt + ZERO_ROW --
__global__ __launch_bounds__(1024) void k_scan_b(int* __restrict__ OFF,
                                                 const int* __restrict__ bsum,
                                                 float* __restrict__ gsum,
                                                 float* __restrict__ gcnt,
                                                 unsigned char* __restrict__ xws) {
    __shared__ int ls[NSB];
    for (int i = threadIdx.x; i < NSB; i += 1024) ls[i] = bsum[i];
    __syncthreads();
    if (threadIdx.x == 0) {
        int run = 0;
        for (int b = 0; b < NSB; b++) { int t = ls[b]; ls[b] = run; run += t; }
    }
    __syncthreads();
    int i = blockIdx.x * 1024 + threadIdx.x;
    OFF[i] += ls[blockIdx.x];
    // fused init work (replaces memsets)
    if (blockIdx.x < 32) gsum[blockIdx.x * 1024 + threadIdx.x] = 0.f;  // 32768 floats
    if (blockIdx.x == 33 && threadIdx.x < N_GRAPHS) gcnt[threadIdx.x] = 0.f;
    if (blockIdx.x == 32 && threadIdx.x < 16)
        ((int*)(xws + (size_t)ZERO_ROW * HID_DIM))[threadIdx.x] = 0;
}

// ---- pass 3: scatter packed edges into bucket-sorted order ---------------
// pk = (col & 63) << 17 | row  (row < 2^17). NB3=256 -> per (block,bucket)
// runs ~8 ints = 32B; swizzled columns keep line-sharing intra-XCD.
__global__ __launch_bounds__(512) void k_scatter(const int* __restrict__ row,
                                                 const int* __restrict__ col,
                                                 const int* __restrict__ OFF,
                                                 int* __restrict__ binned) {
    __shared__ int lofs[NBUCK];
    __shared__ int cur[NBUCK];
    int b = blockIdx.x;
    int bb = xcol(b);
    for (int i = threadIdx.x; i < NBUCK; i += 512) {
        lofs[i] = OFF[i * NB3 + bb];
        cur[i] = 0;
    }
    __syncthreads();
    int s = b * EPB, e = s + EPB;
    for (int i = s + threadIdx.x; i < e; i += 512) {
        int c = col[i];
        int r = row[i];
        int bk = c >> BSHIFT;
        int rk = atomicAdd(&cur[bk], 1);
        binned[lofs[bk] + rk] = ((c & 63) << 17) | r;
    }
}

// ---- xws = (x @ W_gcn) * dinv via MFMA, output fp8 e4m3 ------------------
// Block == bucket: degree hist fused here (k_deg deleted). Hist's global
// loads + LDS atomics issue BEFORE the MFMA loop and complete under it;
// barrier only before the epilogue that needs cnt. cnt spills to degs[]
// for k_aggrf. Wave computes 16-node x 64-col tile with
// mfma_f32_16x16x32_bf16; C/D: col=lane&15, row=quad*4+reg. Epilogue:
// scale by rsqrt(deg+1), pack to fp8 via v_cvt_pk_fp8_f32.
__global__ __launch_bounds__(256) void k_gemm(const float* __restrict__ x,
                                              const float* __restrict__ Wg,
                                              const int* __restrict__ OFF,
                                              const int* __restrict__ binned,
                                              int* __restrict__ degs,
                                              unsigned char* __restrict__ xws) {
    __shared__ unsigned short wb[16][64][8];   // [ks*4+nt][lane][j]  16 KB
    __shared__ int cnt[64];

    if (threadIdx.x < 64) cnt[threadIdx.x] = 0;
    for (int idx = threadIdx.x; idx < 1024; idx += 256) {
        int f = idx >> 6, l = idx & 63;
        int ks = f >> 2, nt = f & 3;
        int n = (l & 15) + (nt << 4);
        int kbase = (ks << 5) + ((l >> 4) << 3);
        unsigned short tmp[8];
#pragma unroll
        for (int j = 0; j < 8; j++)
            tmp[j] = f2bf(Wg[(kbase + j) * HID_DIM + n]);
        *(bf16x8*)&wb[f][l][0] = *(const bf16x8*)tmp;
    }
    __syncthreads();

    int bkt = blockIdx.x;                       // grid 1563: block == bucket
    int s = OFF[bkt * NB3];
    int e = (bkt == NBUCK - 2) ? N_EDGES : OFF[(bkt + 1) * NB3];
    for (int i = s + threadIdx.x; i < e; i += 256)      // deg hist (overlaps MFMA)
        atomicAdd(&cnt[binned[i] >> 17], 1);

    int wave = threadIdx.x >> 6;
    int lane = threadIdx.x & 63;
    int q = lane >> 4, nn = lane & 15;

    bf16x8 bfrag[4][4];
#pragma unroll
    for (int ks = 0; ks < 4; ks++)
#pragma unroll
        for (int nt = 0; nt < 4; nt++)
            bfrag[ks][nt] = *(const bf16x8*)&wb[ks * 4 + nt][lane][0];

    int node0 = bkt * 64 + wave * 16;
    int arow = node0 + nn;
    if (arow > N_NODES - 1) arow = N_NODES - 1;   // clamp (stores predicated)
    const float* xrow = x + (size_t)arow * IN_DIM + (q << 3);

    f32x4 acc[4] = {{0.f,0.f,0.f,0.f},{0.f,0.f,0.f,0.f},
                    {0.f,0.f,0.f,0.f},{0.f,0.f,0.f,0.f}};
#pragma unroll
    for (int ks = 0; ks < 4; ks++) {
        float4 xa = *(const float4*)(xrow + ks * 32);
        float4 xb_ = *(const float4*)(xrow + ks * 32 + 4);
        bf16x8 af;
        af[0] = (short)f2bf(xa.x); af[1] = (short)f2bf(xa.y);
        af[2] = (short)f2bf(xa.z); af[3] = (short)f2bf(xa.w);
        af[4] = (short)f2bf(xb_.x); af[5] = (short)f2bf(xb_.y);
        af[6] = (short)f2bf(xb_.z); af[7] = (short)f2bf(xb_.w);
#pragma unroll
        for (int nt = 0; nt < 4; nt++)
            acc[nt] = __builtin_amdgcn_mfma_f32_16x16x32_bf16(af, bfrag[ks][nt], acc[nt], 0, 0, 0);
    }
    __syncthreads();                                    // cnt hist complete

    if (threadIdx.x < 64) degs[bkt * 64 + threadIdx.x] = cnt[threadIdx.x];

#pragma unroll
    for (int r = 0; r < 4; r++) {
        int lrow = wave * 16 + q * 4 + r;
        int mrow = bkt * 64 + lrow;
        if (mrow < N_NODES) {
            float dn = rsqrtf((float)cnt[lrow] + 1.0f);
            int p01 = __builtin_amdgcn_cvt_pk_fp8_f32(acc[0][r] * dn, acc[1][r] * dn, 0, false);
            int p23 = __builtin_amdgcn_cvt_pk_fp8_f32(acc[2][r] * dn, acc[3][r] * dn, 0, false);
            unsigned char* rp = xws + (size_t)mrow * HID_DIM + nn;
            rp[0]  = (unsigned char)(p01 & 0xff);
            rp[16] = (unsigned char)((p01 >> 8) & 0xff);
            rp[32] = (unsigned char)(p23 & 0xff);
            rp[48] = (unsigned char)((p23 >> 8) & 0xff);
        }
    }
}

// ---- fused local-CSR build + gather-aggregate + ReLU + mean-pool ---------
// 512-thread block per 64-node bucket. Degrees come from degs[] (written
// by k_gemm). srt holds BYTE offsets (row<<6). Subset-per-node gather:
// each 16-lane subset owns ONE node end-to-end -> zero-shuffle epilogue.
// Lists 8-aligned with self-loop folded in; 8 slots/iter (2x ds_read_b128
// + 8 row-loads in flight) with 4 independent accumulator chains.
// Per-graph node counts (gcnt) accumulated here so k_mlp needs no search.
__global__ __launch_bounds__(512) void k_aggrf(const unsigned char* __restrict__ xws,
                                               const int* __restrict__ binned,
                                               const int* __restrict__ OFF,
                                               const int* __restrict__ degs,
                                               const int* __restrict__ batch,
                                               const float* __restrict__ bg,
                                               float* __restrict__ gsum,
                                               float* __restrict__ gcnt) {
    int bkt = blockIdx.x;
    int nbase = bkt << BSHIFT;
    if (nbase >= N_NODES) return;                 // uniform exit (pad bucket)
    int nnodes = N_NODES - nbase; if (nnodes > 64) nnodes = 64;
    int s = OFF[bkt * NB3];
    int e = (bkt == NBUCK - 1) ? N_EDGES : OFF[(bkt + 1) * NB3];
    int m = e - s;

    __shared__ int cnt[64];
    __shared__ int lptr[65];
    __shared__ int cur[64];
    __shared__ int sb[64];
    __shared__ float gcl[8];
    __shared__ alignas(16) int srt[LDS_E2];
    __shared__ float pool[8][4][64];   // [wave][graph-slot][col]

    if (threadIdx.x < 64) {
        int n = nbase + threadIdx.x;
        cnt[threadIdx.x] = (threadIdx.x < nnodes) ? degs[bkt * 64 + threadIdx.x] : 0;
        sb[threadIdx.x]  = (threadIdx.x < nnodes) ? batch[n] : 0;
        cur[threadIdx.x] = 0;
    }
    if (threadIdx.x < 8) gcl[threadIdx.x] = 0.f;
    for (int t = threadIdx.x; t < 8 * 4 * 64; t += 512)
        ((float*)pool)[t] = 0.f;
    __syncthreads();

    // wave-parallel 8-aligned inclusive scan (wave 0); +1 slot for self
    if (threadIdx.x < 64) {
        int v = (threadIdx.x < nnodes) ? ((cnt[threadIdx.x] + 8) & ~7) : 0;
        int run = v;
#pragma unroll
        for (int off = 1; off < 64; off <<= 1) {
            int t = __shfl_up(run, off);
            if (threadIdx.x >= off) run += t;
        }
        lptr[threadIdx.x + 1] = run;
        if (threadIdx.x == 0) lptr[0] = 0;
    }
    __syncthreads();
    int tot = lptr[64]; if (tot > LDS_E2) tot = LDS_E2;
    for (int i = threadIdx.x; i < tot; i += 512) srt[i] = ZERO_ROW << 6;
    __syncthreads();
    // self slot (right after the node's edges) + per-graph node counts
    if (threadIdx.x < nnodes) {
        int p = lptr[threadIdx.x] + cnt[threadIdx.x];
        if (p < LDS_E2) srt[p] = (nbase + threadIdx.x) << 6;
        int sl = sb[threadIdx.x] - sb[0];
        if (sl < 8) atomicAdd(&gcl[sl], 1.0f);
        else atomicAdd(&gcnt[sb[threadIdx.x]], 1.0f);
    }
    for (int i = threadIdx.x; i < m; i += 512) {        // CSR scatter
        int pk = binned[s + i];
        int nid = pk >> 17;
        int rk = atomicAdd(&cur[nid], 1);
        int pos = lptr[nid] + rk;
        if (pos < LDS_E2) srt[pos] = (pk & 0x1FFFF) << 6;   // byte offset
    }
    __syncthreads();

    int wave = threadIdx.x >> 6;
    int lane = threadIdx.x & 63;
    int sub = lane >> 4;                // subset: owns one node at a time
    int lc  = lane & 15;                // lane-in-subset: cols 4lc..4lc+3
    int l4  = lc << 2;                  // byte offset of that dword in a row
    const unsigned char* xbl = xws + l4;
    int g0 = sb[0];
    float4 bia = ((const float4*)bg)[lc];

#pragma unroll
    for (int r = 0; r < 2; r++) {
        int ln = wave * 8 + sub * 2 + r;          // 32 processors x 2 rounds
        int valid = (ln < nnodes);
        int s0 = valid ? lptr[ln] : 0;
        int e0 = valid ? lptr[ln + 1] : 0;
        if (s0 > LDS_E2) s0 = LDS_E2;
        if (e0 > LDS_E2) e0 = LDS_E2;             // both multiples of 8
        f32x2 al0 = {0.f,0.f}, ah0 = {0.f,0.f};   // 4 independent chains
        f32x2 al1 = {0.f,0.f}, ah1 = {0.f,0.f};
        for (int i = s0; i < e0; i += 8) {        // divergent across subsets
            int4 ra = *(const int4*)&srt[i];      // subset-uniform broadcast
            int4 rb = *(const int4*)&srt[i + 4];
            unsigned int d0 = *(const unsigned int*)(xbl + ra.x);
            unsigned int d1 = *(const unsigned int*)(xbl + ra.y);
            unsigned int d2 = *(const unsigned int*)(xbl + ra.z);
            unsigned int d3 = *(const unsigned int*)(xbl + ra.w);
            unsigned int d4 = *(const unsigned int*)(xbl + rb.x);
            unsigned int d5 = *(const unsigned int*)(xbl + rb.y);
            unsigned int d6 = *(const unsigned int*)(xbl + rb.z);
            unsigned int d7 = *(const unsigned int*)(xbl + rb.w);
            f32x2 p;
            p = __builtin_amdgcn_cvt_pk_f32_fp8(d0, false); al0 += p;
            p = __builtin_amdgcn_cvt_pk_f32_fp8(d0, true);  ah0 += p;
            p = __builtin_amdgcn_cvt_pk_f32_fp8(d1, false); al1 += p;
            p = __builtin_amdgcn_cvt_pk_f32_fp8(d1, true);  ah1 += p;
            p = __builtin_amdgcn_cvt_pk_f32_fp8(d2, false); al0 += p;
            p = __builtin_amdgcn_cvt_pk_f32_fp8(d2, true);  ah0 += p;
            p = __builtin_amdgcn_cvt_pk_f32_fp8(d3, false); al1 += p;
            p = __builtin_amdgcn_cvt_pk_f32_fp8(d3, true);  ah1 += p;
            p = __builtin_amdgcn_cvt_pk_f32_fp8(d4, false); al0 += p;
            p = __builtin_amdgcn_cvt_pk_f32_fp8(d4, true);  ah0 += p;
            p = __builtin_amdgcn_cvt_pk_f32_fp8(d5, false); al1 += p;
            p = __builtin_amdgcn_cvt_pk_f32_fp8(d5, true);  ah1 += p;
            p = __builtin_amdgcn_cvt_pk_f32_fp8(d6, false); al0 += p;
            p = __builtin_amdgcn_cvt_pk_f32_fp8(d6, true);  ah0 += p;
            p = __builtin_amdgcn_cvt_pk_f32_fp8(d7, false); al1 += p;
            p = __builtin_amdgcn_cvt_pk_f32_fp8(d7, true);  ah1 += p;
        }
        f32x2 alo = al0 + al1, ahi = ah0 + ah1;
        int slot = 99;
        float4 val;
        if (valid) {
            float dn = rsqrtf((float)cnt[ln] + 1.0f);
            val.x = fmaxf(alo[0] * dn + bia.x, 0.f);
            val.y = fmaxf(alo[1] * dn + bia.y, 0.f);
            val.z = fmaxf(ahi[0] * dn + bia.z, 0.f);
            val.w = fmaxf(ahi[1] * dn + bia.w, 0.f);
            slot = sb[ln] - g0;
        }
        // serialize the 4 subsets' pool RMW (same wave -> in-order LDS ops)
#pragma unroll
        for (int ss = 0; ss < 4; ss++) {
            if (sub == ss && slot < 4) {
                float4* pp = (float4*)&pool[wave][slot][l4];
                float4 pv = *pp;
                pv.x += val.x; pv.y += val.y; pv.z += val.z; pv.w += val.w;
                *pp = pv;
            }
        }
        if (slot >= 4 && slot < 99) {             // rare: >4 graphs in window
            float* gp = &gsum[sb[ln] * HID_DIM + l4];
            atomicAdd(gp + 0, val.x); atomicAdd(gp + 1, val.y);
            atomicAdd(gp + 2, val.z); atomicAdd(gp + 3, val.w);
        }
    }
    __syncthreads();

    if (threadIdx.x < 8) {
        float c = gcl[threadIdx.x];
        if (c != 0.f) atomicAdd(&gcnt[g0 + threadIdx.x], c);
    }
    for (int t = threadIdx.x; t < 4 * 64; t += 512) {
        int slot = t >> 6, j = t & 63;
        float v = 0.f;
#pragma unroll
        for (int w2 = 0; w2 < 8; w2++) v += pool[w2][slot][j];
        if (v != 0.f) atomicAdd(&gsum[(g0 + slot) * HID_DIM + j], v);
    }
}

// ---- divide by counts + MLP + sigmoid (one wave per graph) ---------------
__global__ __launch_bounds__(64) void k_mlp(const float* __restrict__ gsum,
                                            const float* __restrict__ gcnt,
                                            const float* __restrict__ W1,
                                            const float* __restrict__ b1,
                                            const float* __restrict__ W2,
                                            const float* __restrict__ b2,
                                            float* __restrict__ out) {
    int g = blockIdx.x;
    int j = threadIdx.x;
    float cnt = fmaxf(gcnt[g], 1.0f);

    __shared__ float gs[64];
    __shared__ float hs[64];
    gs[j] = gsum[g * 64 + j] / cnt;
    __syncthreads();

    float h = b1[j];
    for (int k = 0; k < 64; k++) h += gs[k] * W1[k * 64 + j];
    hs[j] = fmaxf(h, 0.f);
    __syncthreads();

    if (j < OUT_DIM) {
        float o = b2[j];
        for (int k = 0; k < 64; k++) o += hs[k] * W2[k * OUT_DIM + j];
        out[g * OUT_DIM + j] = 1.f / (1.f + expf(-o));
    }
}

extern "C" void kernel_launch(void* const* d_in, const int* in_sizes, int n_in,
                              void* d_out, int out_size, void* d_ws, size_t ws_size,
                              hipStream_t stream) {
    const float* x   = (const float*)d_in[0];
    const int* eidx  = (const int*)d_in[1];
    const int* batch = (const int*)d_in[2];
    const float* Wg  = (const float*)d_in[3];
    const float* bg  = (const float*)d_in[4];
    const float* W1  = (const float*)d_in[5];
    const float* b1  = (const float*)d_in[6];
    const float* W2  = (const float*)d_in[7];
    const float* b2  = (const float*)d_in[8];
    float* out = (float*)d_out;

    // workspace layout (~23 MB)
    char* w = (char*)d_ws;
    unsigned char* xws = (unsigned char*)w;     w += (size_t)(N_NODES + 1) * HID_DIM;    // 6.4 MB (fp8)
    int*   binned  = (int*)w;                   w += (size_t)N_EDGES * 4;                // 12.8 MB dense
    int*   H       = (int*)w;                   w += (size_t)NBUCK * NB3 * 4;            // 1.6 MB
    int*   OFF     = (int*)w;                   w += (size_t)NBUCK * NB3 * 4;            // 1.6 MB
    int*   bsum    = (int*)w;                   w += NSB * 4;
    int*   degs    = (int*)w;                   w += (size_t)(NBUCK) * 64 * 4;           // 400 KB
    float* gsum    = (float*)w;                 w += N_GRAPHS * HID_DIM * 4;             // 131 KB
    float* gcnt    = (float*)w;                 w += N_GRAPHS * 4;                       // 2 KB

    const int* rowp = eidx;             // edge_index[0] (sources)
    const int* colp = eidx + N_EDGES;   // edge_index[1] (destinations)

    k_hist<<<NB3, 512, 0, stream>>>(colp, H);
    k_scan_a<<<NSB, 1024, 0, stream>>>(H, OFF, bsum);
    k_scan_b<<<NSB, 1024, 0, stream>>>(OFF, bsum, gsum, gcnt, xws);
    k_scatter<<<NB3, 512, 0, stream>>>(rowp, colp, OFF, binned);
    k_gemm<<<(N_NODES + 63) / 64, 256, 0, stream>>>(x, Wg, OFF, binned, degs, xws);
    k_aggrf<<<NBUCK, 512, 0, stream>>>(xws, binned, OFF, degs, batch, bg, gsum, gcnt);
    k_mlp<<<N_GRAPHS, 64, 0, stream>>>(gsum, gcnt, W1, b1, W2, b2, out);
}

// Round 8
// 191.162 us; speedup vs baseline: 1.1973x; 1.0397x over previous
//
#include <hip/hip_runtime.h>

#define N_NODES 100000
#define N_EDGES 3200000
#define IN_DIM 128
#define HID_DIM 64
#define OUT_DIM 2
#define N_GRAPHS 512

#define BSHIFT 6
#define NBK 1563           // ceil(100000/64) buckets of 64 nodes
#define NBB 512            // binning blocks (2/CU by LDS, 16 waves/CU, 1 round)
#define EPB3 6250          // edges per bin-block (512*6250 = 3.2M exact)
#define CAPSHIFT 12        // 4096 slots per bucket in binned (mean ~2046, max ~2300)
#define LDS_E2 2816        // per-bucket LDS edge capacity in aggrf (8-aligned + self)
#define ZERO_ROW N_NODES   // all-zero fp8 row used for alignment padding

__device__ inline unsigned short f2bf(float f) {
    union { float f; unsigned int i; } v; v.f = f;
    unsigned int r = v.i + 0x7fffu + ((v.i >> 16) & 1u);
    return (unsigned short)(r >> 16);
}

typedef __attribute__((ext_vector_type(8))) short bf16x8;
typedef __attribute__((ext_vector_type(4))) float f32x4;
typedef __attribute__((ext_vector_type(2))) float f32x2;

// ---- pass 0: zero cnt_g/gsum/gcnt + ZERO_ROW (replaces all memsets) -----
__global__ __launch_bounds__(1024) void k_init(float* __restrict__ gsum,
                                               int* __restrict__ cnt_g,
                                               float* __restrict__ gcnt,
                                               unsigned char* __restrict__ xws) {
    int b = blockIdx.x, t = threadIdx.x;
    if (b < 32) {
        gsum[b * 1024 + t] = 0.f;                     // 32768 floats
    } else if (b < 34) {
        int j = (b - 32) * 1024 + t;
        if (j < NBK) cnt_g[j] = 0;
    } else {
        if (t < N_GRAPHS) gcnt[t] = 0.f;
        if (t >= 1008)
            ((int*)(xws + (size_t)ZERO_ROW * HID_DIM))[t - 1008] = 0;
    }
}

// ---- pass 1: fused hist + reservation + LDS-staged COALESCED scatter -----
// R4 lesson: occupancy matters (no giant colbuf -> 58.3 KB LDS, 2 blk/CU,
// 16 waves/CU, all 512 blocks resident in one round). R6 lesson: write
// locality matters (4B random scatter -> 7.7x write amplification). Fix:
// sort the block's 6250 edges INTO LDS (sorted+bkt16), then copy out with
// consecutive threads writing consecutive addresses inside each bucket run
// -> dense burst writes. Global base per (block,bucket) via one
// atomicAdd(cnt_g) per nonzero bucket (~650K total, spread over 1563
// addresses). Within-bucket order nondeterministic (always was).
__global__ __launch_bounds__(512) void k_bin(const int* __restrict__ row,
                                             const int* __restrict__ col,
                                             int* __restrict__ cnt_g,
                                             int* __restrict__ binned) {
    __shared__ int h[NBK];             // count -> global run base
    __shared__ int lofs[NBK];          // local exclusive offsets
    __shared__ int cur[NBK];
    __shared__ int ps[512];
    __shared__ int sorted[EPB3];       // 25 KB packed edges, bucket-sorted
    __shared__ unsigned short bkt16[EPB3];  // 12.5 KB slot -> bucket map
    int t = threadIdx.x;
    for (int i = t; i < NBK; i += 512) { h[i] = 0; cur[i] = 0; }
    __syncthreads();
    int s = blockIdx.x * EPB3, e = s + EPB3;
    for (int i = s + t; i < e; i += 512)
        atomicAdd(&h[col[i] >> BSHIFT], 1);
    __syncthreads();
    // block-wide exclusive scan of h[0..NBK) -> lofs (chunk-of-4 + H-S)
    {
        int b0 = t << 2;
        int loc[4];
        int run = 0;
#pragma unroll
        for (int j = 0; j < 4; j++) {
            int b = b0 + j;
            loc[j] = run;
            run += (b < NBK) ? h[b] : 0;
        }
        ps[t] = run;
        __syncthreads();
        for (int off = 1; off < 512; off <<= 1) {
            int v = (t >= off) ? ps[t - off] : 0;
            __syncthreads();
            ps[t] += v;
            __syncthreads();
        }
        int base = (t > 0) ? ps[t - 1] : 0;
#pragma unroll
        for (int j = 0; j < 4; j++) {
            int b = b0 + j;
            if (b < NBK) lofs[b] = base + loc[j];
        }
    }
    __syncthreads();
    // reserve global runs (h becomes the global base for this block's run)
    for (int i = t; i < NBK; i += 512) {
        int hv = h[i];
        if (hv) h[i] = (i << CAPSHIFT) + atomicAdd(&cnt_g[i], hv);
    }
    __syncthreads();
    // scatter into LDS, bucket-sorted (col re-read is L2-warm)
    for (int i = s + t; i < e; i += 512) {
        int c = col[i];
        int r = row[i];
        int bk = c >> BSHIFT;
        int rk = atomicAdd(&cur[bk], 1);
        int p = lofs[bk] + rk;
        sorted[p] = ((c & 63) << 17) | r;      // pk: local nid | src row
        bkt16[p] = (unsigned short)bk;
    }
    __syncthreads();
    // coalesced copy-out: consecutive slots -> consecutive global addrs
    for (int i = t; i < EPB3; i += 512) {
        int bk = bkt16[i];
        binned[h[bk] + (i - lofs[bk])] = sorted[i];
    }
}

// ---- xws = (x @ W_gcn) * dinv via MFMA, output fp8 e4m3 ------------------
// Block == bucket: degree hist fused (k_deg deleted). Hist global loads +
// LDS atomics issue BEFORE the MFMA loop and complete under it; barrier
// only before the epilogue. cnt spills to degs[] for k_aggrf. Wave does a
// 16-node x 64-col tile with mfma_f32_16x16x32_bf16; C/D: col=lane&15,
// row=quad*4+reg.
__global__ __launch_bounds__(256) void k_gemm(const float* __restrict__ x,
                                              const float* __restrict__ Wg,
                                              const int* __restrict__ cnt_g,
                                              const int* __restrict__ binned,
                                              int* __restrict__ degs,
                                              unsigned char* __restrict__ xws) {
    __shared__ unsigned short wb[16][64][8];   // [ks*4+nt][lane][j]  16 KB
    __shared__ int cnt[64];

    if (threadIdx.x < 64) cnt[threadIdx.x] = 0;
    for (int idx = threadIdx.x; idx < 1024; idx += 256) {
        int f = idx >> 6, l = idx & 63;
        int ks = f >> 2, nt = f & 3;
        int n = (l & 15) + (nt << 4);
        int kbase = (ks << 5) + ((l >> 4) << 3);
        unsigned short tmp[8];
#pragma unroll
        for (int j = 0; j < 8; j++)
            tmp[j] = f2bf(Wg[(kbase + j) * HID_DIM + n]);
        *(bf16x8*)&wb[f][l][0] = *(const bf16x8*)tmp;
    }
    __syncthreads();

    int bkt = blockIdx.x;
    int m = cnt_g[bkt];
    for (int i = threadIdx.x; i < m; i += 256)          // deg hist (overlaps MFMA)
        atomicAdd(&cnt[binned[(bkt << CAPSHIFT) + i] >> 17], 1);

    int wave = threadIdx.x >> 6;
    int lane = threadIdx.x & 63;
    int q = lane >> 4, nn = lane & 15;

    bf16x8 bfrag[4][4];
#pragma unroll
    for (int ks = 0; ks < 4; ks++)
#pragma unroll
        for (int nt = 0; nt < 4; nt++)
            bfrag[ks][nt] = *(const bf16x8*)&wb[ks * 4 + nt][lane][0];

    int node0 = bkt * 64 + wave * 16;
    int arow = node0 + nn;
    if (arow > N_NODES - 1) arow = N_NODES - 1;   // clamp (stores predicated)
    const float* xrow = x + (size_t)arow * IN_DIM + (q << 3);

    f32x4 acc[4] = {{0.f,0.f,0.f,0.f},{0.f,0.f,0.f,0.f},
                    {0.f,0.f,0.f,0.f},{0.f,0.f,0.f,0.f}};
#pragma unroll
    for (int ks = 0; ks < 4; ks++) {
        float4 xa = *(const float4*)(xrow + ks * 32);
        float4 xb_ = *(const float4*)(xrow + ks * 32 + 4);
        bf16x8 af;
        af[0] = (short)f2bf(xa.x); af[1] = (short)f2bf(xa.y);
        af[2] = (short)f2bf(xa.z); af[3] = (short)f2bf(xa.w);
        af[4] = (short)f2bf(xb_.x); af[5] = (short)f2bf(xb_.y);
        af[6] = (short)f2bf(xb_.z); af[7] = (short)f2bf(xb_.w);
#pragma unroll
        for (int nt = 0; nt < 4; nt++)
            acc[nt] = __builtin_amdgcn_mfma_f32_16x16x32_bf16(af, bfrag[ks][nt], acc[nt], 0, 0, 0);
    }
    __syncthreads();                                    // cnt hist complete

    if (threadIdx.x < 64) degs[bkt * 64 + threadIdx.x] = cnt[threadIdx.x];

#pragma unroll
    for (int r = 0; r < 4; r++) {
        int lrow = wave * 16 + q * 4 + r;
        int mrow = bkt * 64 + lrow;
        if (mrow < N_NODES) {
            float dn = rsqrtf((float)cnt[lrow] + 1.0f);
            int p01 = __builtin_amdgcn_cvt_pk_fp8_f32(acc[0][r] * dn, acc[1][r] * dn, 0, false);
            int p23 = __builtin_amdgcn_cvt_pk_fp8_f32(acc[2][r] * dn, acc[3][r] * dn, 0, false);
            unsigned char* rp = xws + (size_t)mrow * HID_DIM + nn;
            rp[0]  = (unsigned char)(p01 & 0xff);
            rp[16] = (unsigned char)((p01 >> 8) & 0xff);
            rp[32] = (unsigned char)(p23 & 0xff);
            rp[48] = (unsigned char)((p23 >> 8) & 0xff);
        }
    }
}

// ---- fused local-CSR build + gather-aggregate + ReLU + mean-pool ---------
// 512-thread block per 64-node bucket. Degrees come from degs[] (k_gemm).
// srt holds BYTE offsets (row<<6). Subset-per-node gather: each 16-lane
// subset owns ONE node end-to-end -> zero-shuffle epilogue. Lists
// 8-aligned with self-loop folded in; 8 slots/iter (2x ds_read_b128 + 8
// row-loads in flight) with 4 independent accumulator chains. Per-graph
// node counts (gcnt) accumulated here so k_mlp needs no binary search.
__global__ __launch_bounds__(512) void k_aggrf(const unsigned char* __restrict__ xws,
                                               const int* __restrict__ binned,
                                               const int* __restrict__ cnt_g,
                                               const int* __restrict__ degs,
                                               const int* __restrict__ batch,
                                               const float* __restrict__ bg,
                                               float* __restrict__ gsum,
                                               float* __restrict__ gcnt) {
    int bkt = blockIdx.x;
    int nbase = bkt << BSHIFT;
    int nnodes = N_NODES - nbase; if (nnodes > 64) nnodes = 64;
    int m = cnt_g[bkt];
    int base = bkt << CAPSHIFT;

    __shared__ int cnt[64];
    __shared__ int lptr[65];
    __shared__ int cur[64];
    __shared__ int sb[64];
    __shared__ float gcl[8];
    __shared__ alignas(16) int srt[LDS_E2];
    __shared__ float pool[8][4][64];   // [wave][graph-slot][col]

    if (threadIdx.x < 64) {
        int n = nbase + threadIdx.x;
        cnt[threadIdx.x] = (threadIdx.x < nnodes) ? degs[bkt * 64 + threadIdx.x] : 0;
        sb[threadIdx.x]  = (threadIdx.x < nnodes) ? batch[n] : 0;
        cur[threadIdx.x] = 0;
    }
    if (threadIdx.x < 8) gcl[threadIdx.x] = 0.f;
    for (int t = threadIdx.x; t < 8 * 4 * 64; t += 512)
        ((float*)pool)[t] = 0.f;
    __syncthreads();

    // wave-parallel 8-aligned inclusive scan (wave 0); +1 slot for self
    if (threadIdx.x < 64) {
        int v = (threadIdx.x < nnodes) ? ((cnt[threadIdx.x] + 8) & ~7) : 0;
        int run = v;
#pragma unroll
        for (int off = 1; off < 64; off <<= 1) {
            int t = __shfl_up(run, off);
            if (threadIdx.x >= off) run += t;
        }
        lptr[threadIdx.x + 1] = run;
        if (threadIdx.x == 0) lptr[0] = 0;
    }
    __syncthreads();
    int tot = lptr[64]; if (tot > LDS_E2) tot = LDS_E2;
    for (int i = threadIdx.x; i < tot; i += 512) srt[i] = ZERO_ROW << 6;
    __syncthreads();
    // self slot (right after the node's edges) + per-graph node counts
    if (threadIdx.x < nnodes) {
        int p = lptr[threadIdx.x] + cnt[threadIdx.x];
        if (p < LDS_E2) srt[p] = (nbase + threadIdx.x) << 6;
        int sl = sb[threadIdx.x] - sb[0];
        if (sl < 8) atomicAdd(&gcl[sl], 1.0f);
        else atomicAdd(&gcnt[sb[threadIdx.x]], 1.0f);
    }
    for (int i = threadIdx.x; i < m; i += 512) {        // CSR scatter
        int pk = binned[base + i];
        int nid = pk >> 17;
        int rk = atomicAdd(&cur[nid], 1);
        int pos = lptr[nid] + rk;
        if (pos < LDS_E2) srt[pos] = (pk & 0x1FFFF) << 6;   // byte offset
    }
    __syncthreads();

    int wave = threadIdx.x >> 6;
    int lane = threadIdx.x & 63;
    int sub = lane >> 4;                // subset: owns one node at a time
    int lc  = lane & 15;                // lane-in-subset: cols 4lc..4lc+3
    int l4  = lc << 2;                  // byte offset of that dword in a row
    const unsigned char* xbl = xws + l4;
    int g0 = sb[0];
    float4 bia = ((const float4*)bg)[lc];

#pragma unroll
    for (int r = 0; r < 2; r++) {
        int ln = wave * 8 + sub * 2 + r;          // 32 processors x 2 rounds
        int valid = (ln < nnodes);
        int s0 = valid ? lptr[ln] : 0;
        int e0 = valid ? lptr[ln + 1] : 0;
        if (s0 > LDS_E2) s0 = LDS_E2;
        if (e0 > LDS_E2) e0 = LDS_E2;             // both multiples of 8
        f32x2 al0 = {0.f,0.f}, ah0 = {0.f,0.f};   // 4 independent chains
        f32x2 al1 = {0.f,0.f}, ah1 = {0.f,0.f};
        for (int i = s0; i < e0; i += 8) {        // divergent across subsets
            int4 ra = *(const int4*)&srt[i];      // subset-uniform broadcast
            int4 rb = *(const int4*)&srt[i + 4];
            unsigned int d0 = *(const unsigned int*)(xbl + ra.x);
            unsigned int d1 = *(const unsigned int*)(xbl + ra.y);
            unsigned int d2 = *(const unsigned int*)(xbl + ra.z);
            unsigned int d3 = *(const unsigned int*)(xbl + ra.w);
            unsigned int d4 = *(const unsigned int*)(xbl + rb.x);
            unsigned int d5 = *(const unsigned int*)(xbl + rb.y);
            unsigned int d6 = *(const unsigned int*)(xbl + rb.z);
            unsigned int d7 = *(const unsigned int*)(xbl + rb.w);
            f32x2 p;
            p = __builtin_amdgcn_cvt_pk_f32_fp8(d0, false); al0 += p;
            p = __builtin_amdgcn_cvt_pk_f32_fp8(d0, true);  ah0 += p;
            p = __builtin_amdgcn_cvt_pk_f32_fp8(d1, false); al1 += p;
            p = __builtin_amdgcn_cvt_pk_f32_fp8(d1, true);  ah1 += p;
            p = __builtin_amdgcn_cvt_pk_f32_fp8(d2, false); al0 += p;
            p = __builtin_amdgcn_cvt_pk_f32_fp8(d2, true);  ah0 += p;
            p = __builtin_amdgcn_cvt_pk_f32_fp8(d3, false); al1 += p;
            p = __builtin_amdgcn_cvt_pk_f32_fp8(d3, true);  ah1 += p;
            p = __builtin_amdgcn_cvt_pk_f32_fp8(d4, false); al0 += p;
            p = __builtin_amdgcn_cvt_pk_f32_fp8(d4, true);  ah0 += p;
            p = __builtin_amdgcn_cvt_pk_f32_fp8(d5, false); al1 += p;
            p = __builtin_amdgcn_cvt_pk_f32_fp8(d5, true);  ah1 += p;
            p = __builtin_amdgcn_cvt_pk_f32_fp8(d6, false); al0 += p;
            p = __builtin_amdgcn_cvt_pk_f32_fp8(d6, true);  ah0 += p;
            p = __builtin_amdgcn_cvt_pk_f32_fp8(d7, false); al1 += p;
            p = __builtin_amdgcn_cvt_pk_f32_fp8(d7, true);  ah1 += p;
        }
        f32x2 alo = al0 + al1, ahi = ah0 + ah1;
        int slot = 99;
        float4 val;
        if (valid) {
            float dn = rsqrtf((float)cnt[ln] + 1.0f);
            val.x = fmaxf(alo[0] * dn + bia.x, 0.f);
            val.y = fmaxf(alo[1] * dn + bia.y, 0.f);
            val.z = fmaxf(ahi[0] * dn + bia.z, 0.f);
            val.w = fmaxf(ahi[1] * dn + bia.w, 0.f);
            slot = sb[ln] - g0;
        }
        // serialize the 4 subsets' pool RMW (same wave -> in-order LDS ops)
#pragma unroll
        for (int ss = 0; ss < 4; ss++) {
            if (sub == ss && slot < 4) {
                float4* pp = (float4*)&pool[wave][slot][l4];
                float4 pv = *pp;
                pv.x += val.x; pv.y += val.y; pv.z += val.z; pv.w += val.w;
                *pp = pv;
            }
        }
        if (slot >= 4 && slot < 99) {             // rare: >4 graphs in window
            float* gp = &gsum[sb[ln] * HID_DIM + l4];
            atomicAdd(gp + 0, val.x); atomicAdd(gp + 1, val.y);
            atomicAdd(gp + 2, val.z); atomicAdd(gp + 3, val.w);
        }
    }
    __syncthreads();

    if (threadIdx.x < 8) {
        float c = gcl[threadIdx.x];
        if (c != 0.f) atomicAdd(&gcnt[g0 + threadIdx.x], c);
    }
    for (int t = threadIdx.x; t < 4 * 64; t += 512) {
        int slot = t >> 6, j = t & 63;
        float v = 0.f;
#pragma unroll
        for (int w2 = 0; w2 < 8; w2++) v += pool[w2][slot][j];
        if (v != 0.f) atomicAdd(&gsum[(g0 + slot) * HID_DIM + j], v);
    }
}

// ---- divide by counts + MLP + sigmoid (one wave per graph) ---------------
__global__ __launch_bounds__(64) void k_mlp(const float* __restrict__ gsum,
                                            const float* __restrict__ gcnt,
                                            const float* __restrict__ W1,
                                            const float* __restrict__ b1,
                                            const float* __restrict__ W2,
                                            const float* __restrict__ b2,
                                            float* __restrict__ out) {
    int g = blockIdx.x;
    int j = threadIdx.x;
    float cnt = fmaxf(gcnt[g], 1.0f);

    __shared__ float gs[64];
    __shared__ float hs[64];
    gs[j] = gsum[g * 64 + j] / cnt;
    __syncthreads();

    float h = b1[j];
    for (int k = 0; k < 64; k++) h += gs[k] * W1[k * 64 + j];
    hs[j] = fmaxf(h, 0.f);
    __syncthreads();

    if (j < OUT_DIM) {
        float o = b2[j];
        for (int k = 0; k < 64; k++) o += hs[k] * W2[k * OUT_DIM + j];
        out[g * OUT_DIM + j] = 1.f / (1.f + expf(-o));
    }
}

extern "C" void kernel_launch(void* const* d_in, const int* in_sizes, int n_in,
                              void* d_out, int out_size, void* d_ws, size_t ws_size,
                              hipStream_t stream) {
    const float* x   = (const float*)d_in[0];
    const int* eidx  = (const int*)d_in[1];
    const int* batch = (const int*)d_in[2];
    const float* Wg  = (const float*)d_in[3];
    const float* bg  = (const float*)d_in[4];
    const float* W1  = (const float*)d_in[5];
    const float* b1  = (const float*)d_in[6];
    const float* W2  = (const float*)d_in[7];
    const float* b2  = (const float*)d_in[8];
    float* out = (float*)d_out;

    // workspace layout (~32.6 MB)
    char* w = (char*)d_ws;
    unsigned char* xws = (unsigned char*)w;     w += (size_t)(N_NODES + 1) * HID_DIM;    // 6.4 MB (fp8)
    int*   binned  = (int*)w;                   w += ((size_t)NBK << CAPSHIFT) * 4;      // 25.6 MB fixed-stride
    int*   cnt_g   = (int*)w;                   w += NBK * 4;
    int*   degs    = (int*)w;                   w += (size_t)NBK * 64 * 4;               // 400 KB
    float* gsum    = (float*)w;                 w += N_GRAPHS * HID_DIM * 4;             // 131 KB
    float* gcnt    = (float*)w;                 w += N_GRAPHS * 4;                       // 2 KB

    const int* rowp = eidx;             // edge_index[0] (sources)
    const int* colp = eidx + N_EDGES;   // edge_index[1] (destinations)

    k_init<<<35, 1024, 0, stream>>>(gsum, cnt_g, gcnt, xws);
    k_bin<<<NBB, 512, 0, stream>>>(rowp, colp, cnt_g, binned);
    k_gemm<<<NBK, 256, 0, stream>>>(x, Wg, cnt_g, binned, degs, xws);
    k_aggrf<<<NBK, 512, 0, stream>>>(xws, binned, cnt_g, degs, batch, bg, gsum, gcnt);
    k_mlp<<<N_GRAPHS, 64, 0, stream>>>(gsum, gcnt, W1, b1, W2, b2, out);
}